// Round 5
// baseline (290.957 us; speedup 1.0000x reference)
//
#include <hip/hip_runtime.h>
#include <hip/hip_bf16.h>
#include <math.h>

typedef short bf16x8 __attribute__((ext_vector_type(8)));
typedef float f32x4 __attribute__((ext_vector_type(4)));

#define LROW 72  // padded LDS row (bf16 elems): 144B stride, 2-way alias (free)

__device__ __forceinline__ unsigned short f2bf(float f) {
  union { float f; unsigned int u; } v; v.f = f;
  unsigned int u = v.u;
  unsigned int r = (u + 0x7fffu + ((u >> 16) & 1u)) >> 16;
  return (unsigned short)r;
}

#if __has_builtin(__builtin_amdgcn_global_load_lds)
#define HAVE_GLD 1
__device__ __forceinline__ void gld16(const void* g, void* l) {
  __builtin_amdgcn_global_load_lds(
      (const __attribute__((address_space(1))) unsigned int*)g,
      (__attribute__((address_space(3))) unsigned int*)l, 16, 0, 0);
}
#else
#define HAVE_GLD 0
#endif

// One kernel for all fp32->bf16 conversions: x (4096 blk), Wq(1024), Wk(256), Wv(256), Wproj(1024)
__global__ __launch_bounds__(256) void cvt_all_kernel(const float* __restrict__ x,
                                                      const float* __restrict__ Wq,
                                                      const float* __restrict__ Wk,
                                                      const float* __restrict__ Wv,
                                                      const float* __restrict__ Wproj,
                                                      unsigned short* __restrict__ xb,
                                                      unsigned short* __restrict__ wqkv,
                                                      unsigned short* __restrict__ wpj) {
  int blk = blockIdx.x;
  const float* src;
  unsigned short* dst;
  if (blk < 4096)      { src = x + (size_t)blk * 1024;            dst = xb + (size_t)blk * 1024; }
  else if (blk < 5120) { src = Wq + (size_t)(blk - 4096) * 1024;  dst = wqkv + (size_t)(blk - 4096) * 1024; }
  else if (blk < 5376) { src = Wk + (size_t)(blk - 5120) * 1024;  dst = wqkv + (size_t)(blk - 4096) * 1024; }
  else if (blk < 5632) { src = Wv + (size_t)(blk - 5376) * 1024;  dst = wqkv + (size_t)(blk - 4096) * 1024; }
  else                 { src = Wproj + (size_t)(blk - 5632) * 1024; dst = wpj + (size_t)(blk - 5632) * 1024; }
  int i = threadIdx.x;
  float4 v = ((const float4*)src)[i];
  ushort4 o;
  o.x = f2bf(v.x); o.y = f2bf(v.y); o.z = f2bf(v.z); o.w = f2bf(v.w);
  ((ushort4*)dst)[i] = o;
}

// C[M][N] = A[M][K] x B[N][K]^T ; 128x128 tile, BK=64, global_load_lds(16B) staging,
// XOR-swizzled LDS -> conflict-free b128 reads + contiguous wave-ordered gld dest.
__global__ __launch_bounds__(256) void gemm128_kernel(const unsigned short* __restrict__ A,
                                                      const unsigned short* __restrict__ B,
                                                      float* __restrict__ C, int M, int N, int K) {
  __shared__ unsigned short As[128 * 64];
  __shared__ unsigned short Bs[128 * 64];
  int tid = threadIdx.x;
  int wave = tid >> 6, lane = tid & 63, l15 = lane & 15, quad = lane >> 4;
  int wm = (wave >> 1) * 64, wn = (wave & 1) * 64;
  int n0 = blockIdx.x * 128, m0 = blockIdx.y * 128;
  f32x4 acc[4][4];
#pragma unroll
  for (int i = 0; i < 4; i++)
#pragma unroll
    for (int j = 0; j < 4; j++) acc[i][j] = (f32x4){0.f, 0.f, 0.f, 0.f};
  int srow = lane >> 3;
  int scol = ((lane & 7) ^ srow) * 8;
  for (int k0 = 0; k0 < K; k0 += 64) {
    __syncthreads();
#if HAVE_GLD
#pragma unroll
    for (int i = 0; i < 4; i++) {
      int row = wave * 32 + i * 8;
      gld16(A + (size_t)(m0 + row + srow) * K + k0 + scol, As + row * 64 + lane * 8);
      gld16(B + (size_t)(n0 + row + srow) * K + k0 + scol, Bs + row * 64 + lane * 8);
    }
#else
#pragma unroll
    for (int i = 0; i < 4; i++) {
      int row = wave * 32 + i * 8;
      *(float4*)(As + row * 64 + lane * 8) = *(const float4*)(A + (size_t)(m0 + row + srow) * K + k0 + scol);
      *(float4*)(Bs + row * 64 + lane * 8) = *(const float4*)(B + (size_t)(n0 + row + srow) * K + k0 + scol);
    }
#endif
    __syncthreads();
#pragma unroll
    for (int s = 0; s < 2; s++) {
      bf16x8 af[4], bf[4];
#pragma unroll
      for (int i = 0; i < 4; i++)
        af[i] = *(const bf16x8*)(As + (wm + i * 16 + l15) * 64 + (((s * 4 + quad) ^ (l15 & 7)) * 8));
#pragma unroll
      for (int j = 0; j < 4; j++)
        bf[j] = *(const bf16x8*)(Bs + (wn + j * 16 + l15) * 64 + (((s * 4 + quad) ^ (l15 & 7)) * 8));
#pragma unroll
      for (int i = 0; i < 4; i++)
#pragma unroll
        for (int j = 0; j < 4; j++)
          acc[i][j] = __builtin_amdgcn_mfma_f32_16x16x32_bf16(af[i], bf[j], acc[i][j], 0, 0, 0);
    }
  }
#pragma unroll
  for (int i = 0; i < 4; i++)
#pragma unroll
    for (int j = 0; j < 4; j++)
#pragma unroll
      for (int r = 0; r < 4; r++)
        C[(size_t)(m0 + wm + i * 16 + quad * 4 + r) * N + n0 + wn + j * 16 + l15] = acc[i][j][r];
}

// rope + rms-norm for q,k; gate+ve for v. One block per token, wave per head-slot.
// Q scaled by 1.2*0.125*log2(e), K by 1.2. V written TRANSPOSED [b][kh][d][s].
__global__ __launch_bounds__(256) void qkv_epilogue_kernel(
    const float* __restrict__ qkv, const float* __restrict__ x, const float* __restrict__ ve,
    const float* __restrict__ cosb, const float* __restrict__ sinb,
    const float* __restrict__ wgate, unsigned short* __restrict__ Q,
    unsigned short* __restrict__ K, unsigned short* __restrict__ Vt) {
  int token = blockIdx.x;
  int b = token >> 11, s = token & 2047;
  int wave = threadIdx.x >> 6, d = threadIdx.x & 63;
  float cv = cosb[s * 32 + (d & 31)];
  float sv = sinb[s * 32 + (d & 31)];
  for (int hs = wave; hs < 24; hs += 4) {
    if (hs < 20) {
      bool isq = hs < 16;
      int ch = isq ? hs * 64 + d : 1024 + (hs - 16) * 64 + d;
      float v0 = qkv[(size_t)token * 1536 + ch];
      float other = __shfl_xor(v0, 32, 64);
      float roped = (d < 32) ? fmaf(v0, cv, other * sv) : fmaf(v0, cv, -other * sv);
      float ss = roped * roped;
#pragma unroll
      for (int off = 1; off < 64; off <<= 1) ss += __shfl_xor(ss, off, 64);
      float scale = rsqrtf(ss * (1.0f / 64.0f) + 1.1920929e-07f) * (isq ? 0.216404256f : 1.2f);
      unsigned short o = f2bf(roped * scale);
      if (isq) Q[((size_t)(b * 16 + hs) * 2048 + s) * 64 + d] = o;
      else     K[((size_t)(b * 4 + (hs - 16)) * 2048 + s) * 64 + d] = o;
    } else {
      int kh = hs - 20;
      float vv = qkv[(size_t)token * 1536 + 1280 + kh * 64 + d];
      float dot = 0.f;
#pragma unroll
      for (int j = 0; j < 12; j++) dot += x[(size_t)token * 1024 + j] * wgate[kh * 12 + j];
      float gate = 3.0f / (1.0f + __expf(-dot));
      vv = fmaf(gate, ve[(size_t)token * 256 + kh * 64 + d], vv);
      Vt[((size_t)(b * 4 + kh) * 64 + d) * 2048 + s] = f2bf(vv);
    }
  }
}

// Causal flash attention, GQA 4:1, NO-MAX softmax, SPLIT-K x2, BARRIER-FREE:
// K and V fragments are loaded DIRECTLY from global (64B-coalesced per 16-lane group;
// the 4 waves of a block share the same (kh,kt) stream -> L1/L2 hits). No staging, no
// __syncthreads; only per-wave P LDS round-trip (same-wave DS ordering).
__global__ __launch_bounds__(256) void flash_kernel(const unsigned short* __restrict__ Q,
                                                    const unsigned short* __restrict__ K,
                                                    const unsigned short* __restrict__ Vt,
                                                    unsigned short* __restrict__ accP,
                                                    float* __restrict__ lP) {
  __shared__ unsigned short Ps[4 * 16 * LROW];   // per-wave P [q][key]
  int pair = blockIdx.x, h = blockIdx.y, bc = blockIdx.z;
  int b = bc >> 1, c = bc & 1;
  int hb = b * 16 + h;
  int kh = h >> 2;
  int tid = threadIdx.x, wave = tid >> 6, lane = tid & 63, l15 = lane & 15, quad = lane >> 4;
  // per-lane fragment base pointers
  const unsigned short* Kg = K + (size_t)(b * 4 + kh) * 2048 * 64 + l15 * 64 + quad * 8;
  const unsigned short* Vg = Vt + (size_t)(b * 4 + kh) * 64 * 2048 + l15 * 2048 + quad * 8;
  unsigned short* Pw = Ps + wave * 16 * LROW;

#pragma unroll
  for (int half = 0; half < 2; half++) {
    int qt = (half == 0) ? pair : 31 - pair;
    int c0t = (c == 0) ? 0 : (qt + 2) >> 1;       // key-tile range [c0t, c1t)
    int c1t = (c == 0) ? ((qt + 2) >> 1) : qt + 1;
    int q0 = qt * 64;
    const unsigned short* Qp = Q + (((size_t)hb * 2048) + q0 + wave * 16 + l15) * 64;
    bf16x8 qf0 = *(const bf16x8*)(Qp + quad * 8);
    bf16x8 qf1 = *(const bf16x8*)(Qp + 32 + quad * 8);
    f32x4 acc[4];
#pragma unroll
    for (int i = 0; i < 4; i++) acc[i] = (f32x4){0.f, 0.f, 0.f, 0.f};
    float l_lane = 0.f;

    for (int kt = c0t; kt < c1t; kt++) {
      int k0 = kt * 64;
      // K A-fragments (m=key): rows k0+mt*16+l15, k-halves at +0 / +32
      bf16x8 ka[4], kb[4];
#pragma unroll
      for (int mt = 0; mt < 4; mt++) {
        ka[mt] = *(const bf16x8*)(Kg + (size_t)(k0 + mt * 16) * 64);
        kb[mt] = *(const bf16x8*)(Kg + (size_t)(k0 + mt * 16) * 64 + 32);
      }
      // V B-fragments (n=d): rows d=nt*16+l15 of [d][s], key-halves k0+0 / k0+32
      bf16x8 va[4], vb[4];
#pragma unroll
      for (int nt = 0; nt < 4; nt++) {
        va[nt] = *(const bf16x8*)(Vg + (size_t)nt * 16 * 2048 + k0);
        vb[nt] = *(const bf16x8*)(Vg + (size_t)nt * 16 * 2048 + k0 + 32);
      }
      // S^T: sv[mt][r] = S[q=l15][key = k0 + mt*16 + quad*4 + r]
      f32x4 sv[4];
#pragma unroll
      for (int mt = 0; mt < 4; mt++) {
        sv[mt] = (f32x4){0.f, 0.f, 0.f, 0.f};
        sv[mt] = __builtin_amdgcn_mfma_f32_16x16x32_bf16(ka[mt], qf0, sv[mt], 0, 0, 0);
        sv[mt] = __builtin_amdgcn_mfma_f32_16x16x32_bf16(kb[mt], qf1, sv[mt], 0, 0, 0);
      }
      if (kt == qt) {  // diagonal: causal mask (key > q)
        int qg = q0 + wave * 16 + l15;
#pragma unroll
        for (int mt = 0; mt < 4; mt++) {
          int kg = k0 + mt * 16 + quad * 4;
#pragma unroll
          for (int r = 0; r < 4; r++)
            if (kg + r > qg) sv[mt][r] = -1e30f;
        }
      }
      // p = exp2(s); per-lane l; v_perm truncate-pack 4 consecutive keys -> ds_write_b64
#pragma unroll
      for (int mt = 0; mt < 4; mt++) {
        float p0 = __builtin_amdgcn_exp2f(sv[mt][0]);
        float p1 = __builtin_amdgcn_exp2f(sv[mt][1]);
        float p2 = __builtin_amdgcn_exp2f(sv[mt][2]);
        float p3 = __builtin_amdgcn_exp2f(sv[mt][3]);
        l_lane += (p0 + p1) + (p2 + p3);
        unsigned int lo = __builtin_amdgcn_perm(__float_as_uint(p1), __float_as_uint(p0), 0x07060302u);
        unsigned int hi = __builtin_amdgcn_perm(__float_as_uint(p3), __float_as_uint(p2), 0x07060302u);
        *(uint2*)(Pw + l15 * LROW + mt * 16 + quad * 4) = make_uint2(lo, hi);
      }
      // PV: A = P rows (m=q=l15), B = V^T fragments from regs. Same-wave DS ordering.
      bf16x8 pa0 = *(const bf16x8*)(Pw + l15 * LROW + quad * 8);
      bf16x8 pa1 = *(const bf16x8*)(Pw + l15 * LROW + 32 + quad * 8);
#pragma unroll
      for (int nt = 0; nt < 4; nt++) {
        acc[nt] = __builtin_amdgcn_mfma_f32_16x16x32_bf16(pa0, va[nt], acc[nt], 0, 0, 0);
        acc[nt] = __builtin_amdgcn_mfma_f32_16x16x32_bf16(pa1, vb[nt], acc[nt], 0, 0, 0);
      }
    }
    // reduce l over the 4 lane-groups (same q=l15)
    l_lane += __shfl_xor(l_lane, 16, 64);
    l_lane += __shfl_xor(l_lane, 32, 64);

    size_t slot = (size_t)(c * 32 + hb) * 2048 + q0 + wave * 16;
    if (lane < 16) lP[slot + l15] = l_lane;
    unsigned short* aP = accP + slot * 64;
#pragma unroll
    for (int r = 0; r < 4; r++)
#pragma unroll
      for (int nt = 0; nt < 4; nt++)
        aP[(size_t)(quad * 4 + r) * 64 + nt * 16 + l15] = f2bf(acc[nt][r]);
  }
}

// merge split-K partials: Y = (a0+a1)/(l0+l1), bf16 out. 4 d-elems/thread.
__global__ __launch_bounds__(256) void merge_kernel(const unsigned short* __restrict__ accP,
                                                    const float* __restrict__ lP,
                                                    unsigned short* __restrict__ Y) {
  int t = blockIdx.x * 256 + threadIdx.x;      // 1,048,576 total
  int d4 = (t & 15) * 4;
  int q  = (t >> 4) & 2047;
  int hb = t >> 15;
  const size_t CSTR = (size_t)32 * 2048 * 64;
  size_t pi = ((size_t)hb * 2048 + q) * 64 + d4;
  ushort4 a0 = *(const ushort4*)(accP + pi);
  ushort4 a1 = *(const ushort4*)(accP + pi + CSTR);
  float l = lP[hb * 2048 + q] + lP[32 * 2048 + hb * 2048 + q];
  float inv = 1.f / l;
  float y0 = (__uint_as_float((unsigned)a0.x << 16) + __uint_as_float((unsigned)a1.x << 16)) * inv;
  float y1 = (__uint_as_float((unsigned)a0.y << 16) + __uint_as_float((unsigned)a1.y << 16)) * inv;
  float y2 = (__uint_as_float((unsigned)a0.z << 16) + __uint_as_float((unsigned)a1.z << 16)) * inv;
  float y3 = (__uint_as_float((unsigned)a0.w << 16) + __uint_as_float((unsigned)a1.w << 16)) * inv;
  ushort4 o;
  o.x = f2bf(y0); o.y = f2bf(y1); o.z = f2bf(y2); o.w = f2bf(y3);
  int b = hb >> 4, hh = hb & 15;
  *(ushort4*)(Y + ((size_t)(b * 2048 + q) * 1024) + hh * 64 + d4) = o;
}

extern "C" void kernel_launch(void* const* d_in, const int* in_sizes, int n_in,
                              void* d_out, int out_size, void* d_ws, size_t ws_size,
                              hipStream_t stream) {
  const float* x     = (const float*)d_in[0];
  const float* ve    = (const float*)d_in[1];
  const float* cosb  = (const float*)d_in[2];
  const float* sinb  = (const float*)d_in[3];
  // d_in[4] attn_mask: causal, hard-coded
  const float* Wq    = (const float*)d_in[5];
  const float* Wk    = (const float*)d_in[6];
  const float* Wv    = (const float*)d_in[7];
  const float* Wproj = (const float*)d_in[8];
  const float* Wgate = (const float*)d_in[9];
  float* out = (float*)d_out;
  char* ws = (char*)d_ws;

  size_t o = 0;
  unsigned short* xb   = (unsigned short*)(ws + o); o += (size_t)4096 * 1024 * 2;
  unsigned short* wqkv = (unsigned short*)(ws + o); o += (size_t)1536 * 1024 * 2;
  unsigned short* wpj  = (unsigned short*)(ws + o); o += (size_t)1024 * 1024 * 2;
  char*           qkvr = ws + o;                    o += (size_t)4096 * 1536 * 4;   // qkv fp32 / flash partials
  unsigned short* Qb   = (unsigned short*)(ws + o); o += (size_t)2 * 16 * 2048 * 64 * 2;
  unsigned short* Kb   = (unsigned short*)(ws + o); o += (size_t)2 * 4 * 2048 * 64 * 2;
  unsigned short* Vb   = (unsigned short*)(ws + o); o += (size_t)2 * 4 * 2048 * 64 * 2; // transposed
  unsigned short* Yb   = (unsigned short*)(ws + o); o += (size_t)4096 * 1024 * 2;

  float* qkvf = (float*)qkvr;
  unsigned short* accP = (unsigned short*)qkvr;
  float* lP = (float*)(qkvr + (size_t)2 * 2 * 16 * 2048 * 64 * 2);

  hipLaunchKernelGGL(cvt_all_kernel, dim3(6656), dim3(256), 0, stream,
                     x, Wq, Wk, Wv, Wproj, xb, wqkv, wpj);
  hipLaunchKernelGGL(gemm128_kernel, dim3(12, 32), dim3(256), 0, stream, xb, wqkv, qkvf, 4096, 1536, 1024);
  hipLaunchKernelGGL(qkv_epilogue_kernel, dim3(4096), dim3(256), 0, stream,
                     qkvf, x, ve, cosb, sinb, Wgate, Qb, Kb, Vb);
  hipLaunchKernelGGL(flash_kernel, dim3(16, 16, 4), dim3(256), 0, stream, Qb, Kb, Vb, accP, lP);
  hipLaunchKernelGGL(merge_kernel, dim3(4096), dim3(256), 0, stream, accP, lP, Yb);
  hipLaunchKernelGGL(gemm128_kernel, dim3(8, 32), dim3(256), 0, stream, Yb, wpj, out, 4096, 1024, 1024);
}

// Round 6
// 200.250 us; speedup vs baseline: 1.4530x; 1.4530x over previous
//
#include <hip/hip_runtime.h>
#include <hip/hip_bf16.h>
#include <math.h>

typedef short bf16x8 __attribute__((ext_vector_type(8)));
typedef float f32x4 __attribute__((ext_vector_type(4)));

#define LROW 72  // padded LDS row (bf16 elems): 144B stride, 2-way alias (free)

__device__ __forceinline__ unsigned short f2bf(float f) {
  union { float f; unsigned int u; } v; v.f = f;
  unsigned int u = v.u;
  unsigned int r = (u + 0x7fffu + ((u >> 16) & 1u)) >> 16;
  return (unsigned short)r;
}
__device__ __forceinline__ float bf2f(unsigned short u) {
  return __uint_as_float((unsigned)u << 16);
}

#if __has_builtin(__builtin_amdgcn_global_load_lds)
#define HAVE_GLD 1
__device__ __forceinline__ void gld16(const void* g, void* l) {
  __builtin_amdgcn_global_load_lds(
      (const __attribute__((address_space(1))) unsigned int*)g,
      (__attribute__((address_space(3))) unsigned int*)l, 16, 0, 0);
}
#else
#define HAVE_GLD 0
#endif

// All fp32->bf16 converts: x (4096 blk), Wq(1024), Wk(256), Wv(256), Wproj(1024)
__global__ __launch_bounds__(256) void cvt_all_kernel(const float* __restrict__ x,
                                                      const float* __restrict__ Wq,
                                                      const float* __restrict__ Wk,
                                                      const float* __restrict__ Wv,
                                                      const float* __restrict__ Wproj,
                                                      unsigned short* __restrict__ xb,
                                                      unsigned short* __restrict__ wqkv,
                                                      unsigned short* __restrict__ wpj) {
  int blk = blockIdx.x;
  const float* src;
  unsigned short* dst;
  if (blk < 4096)      { src = x + (size_t)blk * 1024;            dst = xb + (size_t)blk * 1024; }
  else if (blk < 5120) { src = Wq + (size_t)(blk - 4096) * 1024;  dst = wqkv + (size_t)(blk - 4096) * 1024; }
  else if (blk < 5376) { src = Wk + (size_t)(blk - 5120) * 1024;  dst = wqkv + (size_t)(blk - 4096) * 1024; }
  else if (blk < 5632) { src = Wv + (size_t)(blk - 5376) * 1024;  dst = wqkv + (size_t)(blk - 4096) * 1024; }
  else                 { src = Wproj + (size_t)(blk - 5632) * 1024; dst = wpj + (size_t)(blk - 5632) * 1024; }
  int i = threadIdx.x;
  float4 v = ((const float4*)src)[i];
  ushort4 o;
  o.x = f2bf(v.x); o.y = f2bf(v.y); o.z = f2bf(v.z); o.w = f2bf(v.w);
  ((ushort4*)dst)[i] = o;
}

// Plain GEMM C[M][N] = A[M][K] x B[N][K]^T; 128x128 tile, BK=64, gld16 staging, XOR swizzle.
__global__ __launch_bounds__(256) void gemm128_kernel(const unsigned short* __restrict__ A,
                                                      const unsigned short* __restrict__ B,
                                                      float* __restrict__ C, int M, int N, int K) {
  __shared__ unsigned short As[128 * 64];
  __shared__ unsigned short Bs[128 * 64];
  int tid = threadIdx.x;
  int wave = tid >> 6, lane = tid & 63, l15 = lane & 15, quad = lane >> 4;
  int wm = (wave >> 1) * 64, wn = (wave & 1) * 64;
  int n0 = blockIdx.x * 128, m0 = blockIdx.y * 128;
  f32x4 acc[4][4];
#pragma unroll
  for (int i = 0; i < 4; i++)
#pragma unroll
    for (int j = 0; j < 4; j++) acc[i][j] = (f32x4){0.f, 0.f, 0.f, 0.f};
  int srow = lane >> 3;
  int scol = ((lane & 7) ^ srow) * 8;
  for (int k0 = 0; k0 < K; k0 += 64) {
    __syncthreads();
#if HAVE_GLD
#pragma unroll
    for (int i = 0; i < 4; i++) {
      int row = wave * 32 + i * 8;
      gld16(A + (size_t)(m0 + row + srow) * K + k0 + scol, As + row * 64 + lane * 8);
      gld16(B + (size_t)(n0 + row + srow) * K + k0 + scol, Bs + row * 64 + lane * 8);
    }
#else
#pragma unroll
    for (int i = 0; i < 4; i++) {
      int row = wave * 32 + i * 8;
      *(float4*)(As + row * 64 + lane * 8) = *(const float4*)(A + (size_t)(m0 + row + srow) * K + k0 + scol);
      *(float4*)(Bs + row * 64 + lane * 8) = *(const float4*)(B + (size_t)(n0 + row + srow) * K + k0 + scol);
    }
#endif
    __syncthreads();
#pragma unroll
    for (int s = 0; s < 2; s++) {
      bf16x8 af[4], bf[4];
#pragma unroll
      for (int i = 0; i < 4; i++)
        af[i] = *(const bf16x8*)(As + (wm + i * 16 + l15) * 64 + (((s * 4 + quad) ^ (l15 & 7)) * 8));
#pragma unroll
      for (int j = 0; j < 4; j++)
        bf[j] = *(const bf16x8*)(Bs + (wn + j * 16 + l15) * 64 + (((s * 4 + quad) ^ (l15 & 7)) * 8));
#pragma unroll
      for (int i = 0; i < 4; i++)
#pragma unroll
        for (int j = 0; j < 4; j++)
          acc[i][j] = __builtin_amdgcn_mfma_f32_16x16x32_bf16(af[i], bf[j], acc[i][j], 0, 0, 0);
    }
  }
#pragma unroll
  for (int i = 0; i < 4; i++)
#pragma unroll
    for (int j = 0; j < 4; j++)
#pragma unroll
      for (int r = 0; r < 4; r++)
        C[(size_t)(m0 + wm + i * 16 + quad * 4 + r) * N + n0 + wn + j * 16 + l15] = acc[i][j][r];
}

// Fused qkv GEMM (M=4096,N=1536,K=1024) + rope/rms/gate epilogue.
// Each wave's 64 cols = one head-slot hs=(n0+wn)>>6: 0-15 Q, 16-19 K, 20-23 V.
// Rope pair (d,d+32) = (acc[i][j], acc[i][j+2]) same lane; rms = 4-step l15 butterfly.
// Q scaled 1.2*0.125*log2(e) (exp2-domain fold), K 1.2. V += gate*ve, written [b][kh][d][s].
__global__ __launch_bounds__(256) void gemm_qkv_kernel(const unsigned short* __restrict__ A,
                                                       const unsigned short* __restrict__ B,
                                                       const float* __restrict__ ve,
                                                       const float* __restrict__ cosb,
                                                       const float* __restrict__ sinb,
                                                       const float* __restrict__ wgate,
                                                       unsigned short* __restrict__ Q,
                                                       unsigned short* __restrict__ Kd,
                                                       unsigned short* __restrict__ Vt) {
  __shared__ unsigned short As[128 * 64];
  __shared__ unsigned short Bs[128 * 64];
  __shared__ float gLDS[256];
  const int K = 1024;
  int tid = threadIdx.x;
  int wave = tid >> 6, lane = tid & 63, l15 = lane & 15, quad = lane >> 4;
  int wm = (wave >> 1) * 64, wn = (wave & 1) * 64;
  int n0 = blockIdx.x * 128, m0 = blockIdx.y * 128;
  // gate precompute for V-blocks (n0 >= 1280): gLDS[khl*128+row] = 3*sigmoid(x[:12]@Wgate[kh])
  if (n0 >= 1280) {
    int rl = tid & 127, khl2 = tid >> 7;
    int kh = ((n0 >> 6) - 20) + khl2;
    float dot = 0.f;
#pragma unroll
    for (int jj = 0; jj < 12; jj++)
      dot += bf2f(A[(size_t)(m0 + rl) * 1024 + jj]) * wgate[kh * 12 + jj];
    gLDS[khl2 * 128 + rl] = 3.0f / (1.0f + __expf(-dot));
  }
  f32x4 acc[4][4];
#pragma unroll
  for (int i = 0; i < 4; i++)
#pragma unroll
    for (int j = 0; j < 4; j++) acc[i][j] = (f32x4){0.f, 0.f, 0.f, 0.f};
  int srow = lane >> 3;
  int scol = ((lane & 7) ^ srow) * 8;
  for (int k0 = 0; k0 < K; k0 += 64) {
    __syncthreads();
#if HAVE_GLD
#pragma unroll
    for (int i = 0; i < 4; i++) {
      int row = wave * 32 + i * 8;
      gld16(A + (size_t)(m0 + row + srow) * K + k0 + scol, As + row * 64 + lane * 8);
      gld16(B + (size_t)(n0 + row + srow) * K + k0 + scol, Bs + row * 64 + lane * 8);
    }
#else
#pragma unroll
    for (int i = 0; i < 4; i++) {
      int row = wave * 32 + i * 8;
      *(float4*)(As + row * 64 + lane * 8) = *(const float4*)(A + (size_t)(m0 + row + srow) * K + k0 + scol);
      *(float4*)(Bs + row * 64 + lane * 8) = *(const float4*)(B + (size_t)(n0 + row + srow) * K + k0 + scol);
    }
#endif
    __syncthreads();
#pragma unroll
    for (int s = 0; s < 2; s++) {
      bf16x8 af[4], bf[4];
#pragma unroll
      for (int i = 0; i < 4; i++)
        af[i] = *(const bf16x8*)(As + (wm + i * 16 + l15) * 64 + (((s * 4 + quad) ^ (l15 & 7)) * 8));
#pragma unroll
      for (int j = 0; j < 4; j++)
        bf[j] = *(const bf16x8*)(Bs + (wn + j * 16 + l15) * 64 + (((s * 4 + quad) ^ (l15 & 7)) * 8));
#pragma unroll
      for (int i = 0; i < 4; i++)
#pragma unroll
        for (int j = 0; j < 4; j++)
          acc[i][j] = __builtin_amdgcn_mfma_f32_16x16x32_bf16(af[i], bf[j], acc[i][j], 0, 0, 0);
    }
  }
  int hs = (n0 + wn) >> 6;
  if (hs < 20) {
    bool isq = hs < 16;
    float postscale = isq ? 0.216404256f : 1.2f;
#pragma unroll
    for (int i = 0; i < 4; i++) {
#pragma unroll
      for (int r = 0; r < 4; r++) {
        int row = m0 + wm + i * 16 + quad * 4 + r;
        int s = row & 2047, b = row >> 11;
        float c0 = cosb[s * 32 + l15],      s0 = sinb[s * 32 + l15];
        float c1 = cosb[s * 32 + 16 + l15], s1 = sinb[s * 32 + 16 + l15];
        float v0 = acc[i][0][r], v1 = acc[i][1][r], v2 = acc[i][2][r], v3 = acc[i][3][r];
        float n0v = fmaf(v0, c0,  v2 * s0);
        float n1v = fmaf(v1, c1,  v3 * s1);
        float n2v = fmaf(v2, c0, -v0 * s0);
        float n3v = fmaf(v3, c1, -v1 * s1);
        float ss = (n0v * n0v + n1v * n1v) + (n2v * n2v + n3v * n3v);
        ss += __shfl_xor(ss, 1, 64); ss += __shfl_xor(ss, 2, 64);
        ss += __shfl_xor(ss, 4, 64); ss += __shfl_xor(ss, 8, 64);
        float sc = rsqrtf(ss * (1.0f / 64.0f) + 1.1920929e-07f) * postscale;
        unsigned short* dp = isq ? Q + ((size_t)(b * 16 + hs) * 2048 + s) * 64
                                 : Kd + ((size_t)(b * 4 + hs - 16) * 2048 + s) * 64;
        dp[l15]      = f2bf(n0v * sc);
        dp[16 + l15] = f2bf(n1v * sc);
        dp[32 + l15] = f2bf(n2v * sc);
        dp[48 + l15] = f2bf(n3v * sc);
      }
    }
  } else {
    int khl = wave & 1;
    int kh = hs - 20;
#pragma unroll
    for (int i = 0; i < 4; i++) {
#pragma unroll
      for (int r = 0; r < 4; r++) {
        int rl = wm + i * 16 + quad * 4 + r;
        int row = m0 + rl, s = row & 2047, b = row >> 11;
        float g = gLDS[khl * 128 + rl];
        const float* vep = ve + (size_t)row * 256 + kh * 64;
        unsigned short* vp = Vt + ((size_t)(b * 4 + kh) * 64) * 2048 + s;
#pragma unroll
        for (int j = 0; j < 4; j++) {
          float vv = fmaf(g, vep[j * 16 + l15], acc[i][j][r]);
          vp[(size_t)(j * 16 + l15) * 2048] = f2bf(vv);
        }
      }
    }
  }
}

// Causal flash attention, GQA 4:1, NO-MAX softmax, SPLIT-K x4 (exp2-domain partials:
// merge = plain add). Block = (pair, h, b*4+c); q-tiles {pair, 31-pair}, key chunk c.
__global__ __launch_bounds__(256) void flash_kernel(const unsigned short* __restrict__ Q,
                                                    const unsigned short* __restrict__ K,
                                                    const unsigned short* __restrict__ Vt,
                                                    unsigned short* __restrict__ accP,
                                                    float* __restrict__ lP) {
  __shared__ unsigned short Ks[64 * LROW];       // [key][dim]
  __shared__ unsigned short Vs[64 * LROW];       // [dim][key]
  __shared__ unsigned short Ps[4 * 16 * LROW];   // per-wave P [q][key]
  int pair = blockIdx.x, h = blockIdx.y, bc = blockIdx.z;
  int b = bc >> 2, c = bc & 3;
  int hb = b * 16 + h;
  int kh = h >> 2;
  int tid = threadIdx.x, wave = tid >> 6, lane = tid & 63, l15 = lane & 15, quad = lane >> 4;
  const unsigned short* Kg = K + (size_t)(b * 4 + kh) * 2048 * 64;
  const unsigned short* Vg = Vt + (size_t)(b * 4 + kh) * 64 * 2048;
  unsigned short* Pw = Ps + wave * 16 * LROW;
  int row0 = tid >> 3, col8 = (tid & 7) * 8;

#pragma unroll
  for (int half = 0; half < 2; half++) {
    int qt = (half == 0) ? pair : 31 - pair;
    int c0t = ((qt + 1) * c) >> 2;
    int c1t = ((qt + 1) * (c + 1)) >> 2;
    int q0 = qt * 64;
    const unsigned short* Qp = Q + (((size_t)hb * 2048) + q0 + wave * 16 + l15) * 64;
    bf16x8 qf0 = *(const bf16x8*)(Qp + quad * 8);
    bf16x8 qf1 = *(const bf16x8*)(Qp + 32 + quad * 8);
    f32x4 acc[4];
#pragma unroll
    for (int i = 0; i < 4; i++) acc[i] = (f32x4){0.f, 0.f, 0.f, 0.f};
    float l_lane = 0.f;

    if (c1t > c0t) {
      int kf = c0t * 64;
      float4 pk0 = *(const float4*)(Kg + (size_t)(kf + row0) * 64 + col8);
      float4 pk1 = *(const float4*)(Kg + (size_t)(kf + row0 + 32) * 64 + col8);
      float4 pv0 = *(const float4*)(Vg + (size_t)row0 * 2048 + kf + col8);
      float4 pv1 = *(const float4*)(Vg + (size_t)(row0 + 32) * 2048 + kf + col8);

      for (int kt = c0t; kt < c1t; kt++) {
        int k0 = kt * 64;
        __syncthreads();
        *(float4*)(Ks + row0 * LROW + col8) = pk0;
        *(float4*)(Ks + (row0 + 32) * LROW + col8) = pk1;
        *(float4*)(Vs + row0 * LROW + col8) = pv0;
        *(float4*)(Vs + (row0 + 32) * LROW + col8) = pv1;
        if (kt + 1 < c1t) {
          int kn = k0 + 64;
          pk0 = *(const float4*)(Kg + (size_t)(kn + row0) * 64 + col8);
          pk1 = *(const float4*)(Kg + (size_t)(kn + row0 + 32) * 64 + col8);
          pv0 = *(const float4*)(Vg + (size_t)row0 * 2048 + kn + col8);
          pv1 = *(const float4*)(Vg + (size_t)(row0 + 32) * 2048 + kn + col8);
        }
        __syncthreads();

        // S^T: sv[mt][r] = S[q=l15][key=k0+mt*16+quad*4+r]
        f32x4 sv[4];
#pragma unroll
        for (int mt = 0; mt < 4; mt++) {
          sv[mt] = (f32x4){0.f, 0.f, 0.f, 0.f};
          bf16x8 k0f = *(const bf16x8*)(Ks + (mt * 16 + l15) * LROW + quad * 8);
          sv[mt] = __builtin_amdgcn_mfma_f32_16x16x32_bf16(k0f, qf0, sv[mt], 0, 0, 0);
          bf16x8 k1f = *(const bf16x8*)(Ks + (mt * 16 + l15) * LROW + 32 + quad * 8);
          sv[mt] = __builtin_amdgcn_mfma_f32_16x16x32_bf16(k1f, qf1, sv[mt], 0, 0, 0);
        }
        if (kt == qt) {  // diagonal: causal mask (key > q)
          int qg = q0 + wave * 16 + l15;
#pragma unroll
          for (int mt = 0; mt < 4; mt++) {
            int kg = k0 + mt * 16 + quad * 4;
#pragma unroll
            for (int r = 0; r < 4; r++)
              if (kg + r > qg) sv[mt][r] = -1e30f;
          }
        }
#pragma unroll
        for (int mt = 0; mt < 4; mt++) {
          float p0 = __builtin_amdgcn_exp2f(sv[mt][0]);
          float p1 = __builtin_amdgcn_exp2f(sv[mt][1]);
          float p2 = __builtin_amdgcn_exp2f(sv[mt][2]);
          float p3 = __builtin_amdgcn_exp2f(sv[mt][3]);
          l_lane += (p0 + p1) + (p2 + p3);
          unsigned int lo = __builtin_amdgcn_perm(__float_as_uint(p1), __float_as_uint(p0), 0x07060302u);
          unsigned int hi = __builtin_amdgcn_perm(__float_as_uint(p3), __float_as_uint(p2), 0x07060302u);
          *(uint2*)(Pw + l15 * LROW + mt * 16 + quad * 4) = make_uint2(lo, hi);
        }
        // PV: same-wave DS ordering, no barrier.
#pragma unroll
        for (int step = 0; step < 2; step++) {
          bf16x8 pa = *(const bf16x8*)(Pw + l15 * LROW + step * 32 + quad * 8);
#pragma unroll
          for (int nt = 0; nt < 4; nt++) {
            bf16x8 vb = *(const bf16x8*)(Vs + (nt * 16 + l15) * LROW + step * 32 + quad * 8);
            acc[nt] = __builtin_amdgcn_mfma_f32_16x16x32_bf16(pa, vb, acc[nt], 0, 0, 0);
          }
        }
      }
    }
    l_lane += __shfl_xor(l_lane, 16, 64);
    l_lane += __shfl_xor(l_lane, 32, 64);

    size_t slot = (size_t)(c * 32 + hb) * 2048 + q0 + wave * 16;
    if (lane < 16) lP[slot + l15] = l_lane;
    unsigned short* aP = accP + slot * 64;
#pragma unroll
    for (int r = 0; r < 4; r++)
#pragma unroll
      for (int nt = 0; nt < 4; nt++)
        aP[(size_t)(quad * 4 + r) * 64 + nt * 16 + l15] = f2bf(acc[nt][r]);
  }
}

// merge 4 split-K partials: Y = (Σa_c)/(Σl_c), bf16 out. 4 d-elems/thread.
__global__ __launch_bounds__(256) void merge_kernel(const unsigned short* __restrict__ accP,
                                                    const float* __restrict__ lP,
                                                    unsigned short* __restrict__ Y) {
  int t = blockIdx.x * 256 + threadIdx.x;
  int d4 = (t & 15) * 4;
  int q  = (t >> 4) & 2047;
  int hb = t >> 15;
  const size_t CSTR = (size_t)32 * 2048 * 64;
  size_t pi = ((size_t)hb * 2048 + q) * 64 + d4;
  float y0 = 0.f, y1 = 0.f, y2 = 0.f, y3 = 0.f, l = 0.f;
#pragma unroll
  for (int c = 0; c < 4; c++) {
    ushort4 a = *(const ushort4*)(accP + pi + c * CSTR);
    y0 += bf2f(a.x); y1 += bf2f(a.y); y2 += bf2f(a.z); y3 += bf2f(a.w);
    l += lP[c * 65536 + hb * 2048 + q];
  }
  float inv = 1.f / l;
  ushort4 o;
  o.x = f2bf(y0 * inv); o.y = f2bf(y1 * inv); o.z = f2bf(y2 * inv); o.w = f2bf(y3 * inv);
  int b = hb >> 4, hh = hb & 15;
  *(ushort4*)(Y + ((size_t)(b * 2048 + q) * 1024) + hh * 64 + d4) = o;
}

extern "C" void kernel_launch(void* const* d_in, const int* in_sizes, int n_in,
                              void* d_out, int out_size, void* d_ws, size_t ws_size,
                              hipStream_t stream) {
  const float* x     = (const float*)d_in[0];
  const float* ve    = (const float*)d_in[1];
  const float* cosb  = (const float*)d_in[2];
  const float* sinb  = (const float*)d_in[3];
  // d_in[4] attn_mask: causal, hard-coded
  const float* Wq    = (const float*)d_in[5];
  const float* Wk    = (const float*)d_in[6];
  const float* Wv    = (const float*)d_in[7];
  const float* Wproj = (const float*)d_in[8];
  const float* Wgate = (const float*)d_in[9];
  float* out = (float*)d_out;
  char* ws = (char*)d_ws;

  size_t o = 0;
  unsigned short* xb   = (unsigned short*)(ws + o); o += (size_t)4096 * 1024 * 2;
  unsigned short* wqkv = (unsigned short*)(ws + o); o += (size_t)1536 * 1024 * 2;
  unsigned short* wpj  = (unsigned short*)(ws + o); o += (size_t)1024 * 1024 * 2;
  unsigned short* Qb   = (unsigned short*)(ws + o); o += (size_t)2 * 16 * 2048 * 64 * 2;
  unsigned short* Kb   = (unsigned short*)(ws + o); o += (size_t)2 * 4 * 2048 * 64 * 2;
  unsigned short* Vb   = (unsigned short*)(ws + o); o += (size_t)2 * 4 * 2048 * 64 * 2; // [b][kh][d][s]
  unsigned short* Yb   = (unsigned short*)(ws + o); o += (size_t)4096 * 1024 * 2;
  unsigned short* accP = (unsigned short*)(ws + o); o += (size_t)4 * 32 * 2048 * 64 * 2;
  float*          lP   = (float*)(ws + o);          o += (size_t)4 * 32 * 2048 * 4;

  hipLaunchKernelGGL(cvt_all_kernel, dim3(6656), dim3(256), 0, stream,
                     x, Wq, Wk, Wv, Wproj, xb, wqkv, wpj);
  hipLaunchKernelGGL(gemm_qkv_kernel, dim3(12, 32), dim3(256), 0, stream,
                     xb, wqkv, ve, cosb, sinb, Wgate, Qb, Kb, Vb);
  hipLaunchKernelGGL(flash_kernel, dim3(16, 16, 8), dim3(256), 0, stream, Qb, Kb, Vb, accP, lP);
  hipLaunchKernelGGL(merge_kernel, dim3(4096), dim3(256), 0, stream, accP, lP, Yb);
  hipLaunchKernelGGL(gemm128_kernel, dim3(8, 32), dim3(256), 0, stream, Yb, wpj, out, 4096, 1024, 1024);
}